// Round 5
// baseline (307.091 us; speedup 1.0000x reference)
//
#include <hip/hip_runtime.h>
#include <hip/hip_bf16.h>
#include <stdint.h>
#include <stddef.h>

// Problem constants
#define B_ 32
#define N_ 1024
#define C_ 768
#define H_ 12
#define D_ 64
#define M_ (B_*N_)     // 32768 rows
#define TC_ (3*C_)     // 2304 qkv cols

typedef __bf16 bf16_t;
typedef __attribute__((ext_vector_type(8))) __bf16 bf16x8;
typedef __attribute__((ext_vector_type(4))) __bf16 bf16x4;
typedef __attribute__((ext_vector_type(4))) float  f32x4;

#define MFMA16(a,b,c) __builtin_amdgcn_mfma_f32_16x16x32_bf16(a,b,c,0,0,0)

__device__ __forceinline__ void lds_load16(const void* g, void* l) {
  __builtin_amdgcn_global_load_lds(
      (const __attribute__((address_space(1))) void*)g,
      (__attribute__((address_space(3))) void*)l, 16, 0, 0);
}

// ---------------------------------------------------------------- converts
__global__ void cvt_bf16(const float* __restrict__ in, bf16_t* __restrict__ out, int n) {
  int i = (blockIdx.x * 256 + threadIdx.x) * 8;
  if (i >= n) return;
  const float4 a = *(const float4*)(in + i);
  const float4 b = *(const float4*)(in + i + 4);
  bf16x8 r;
  r[0]=(bf16_t)a.x; r[1]=(bf16_t)a.y; r[2]=(bf16_t)a.z; r[3]=(bf16_t)a.w;
  r[4]=(bf16_t)b.x; r[5]=(bf16_t)b.y; r[6]=(bf16_t)b.z; r[7]=(bf16_t)b.w;
  *(bf16x8*)(out + i) = r;
}

// out[c][r] = bf16(in[r][c]); grid (Cc/32, R/32), 256 threads
__global__ void transpose_cvt(const float* __restrict__ in, bf16_t* __restrict__ out,
                              int R, int Cc) {
  __shared__ float t[32][33];
  const int c0 = blockIdx.x * 32, r0 = blockIdx.y * 32;
  const int tx = threadIdx.x & 31, ty = threadIdx.x >> 5;  // ty 0..7
  #pragma unroll
  for (int k = 0; k < 4; ++k)
    t[ty + k*8][tx] = in[(size_t)(r0 + ty + k*8)*Cc + c0 + tx];
  __syncthreads();
  #pragma unroll
  for (int k = 0; k < 4; ++k)
    out[(size_t)(c0 + ty + k*8)*R + r0 + tx] = (bf16_t)t[tx][ty + k*8];
}

// ---------------------------------------------------------------- GEMM 256x256, BK=32, 8 waves
// 4-buffer LDS ring (4 x 32KB = 128KB), prefetch depth 3, boundary vmcnt(8)+barrier.
// Wave tile 128x64 (waves 2 row x 4 col). K = 768 = 24 K-tiles.
// LDS per buffer: A[256][32] (16KB) then B[256][32] (16KB). Rows are 64B ->
// a wave's 16-row fragment read is one contiguous 1024B block (bank-floor, no swizzle).
// MODE 1: qkv scatter epilogue (q -> (b,h,n,d); k,v -> (b,h,d,n)), bf16 + bias
// MODE 3: out projection; A = qh gathered as (b*1024+n, h*64+d); fp32 out + bias;
//         BT per-batch stride 768*768.
template<int MODE>
__global__ __launch_bounds__(512, 2)
void gemm_bt(const bf16_t* __restrict__ A, const bf16_t* __restrict__ BT,
             const float* __restrict__ bias, float* __restrict__ Cout,
             bf16_t* __restrict__ qh,
             bf16_t* __restrict__ kthi, bf16_t* __restrict__ vthi,
             int nbx)
{
  __shared__ __align__(16) char smem[131072];

  const int nwg = gridDim.x;
  const int cpx = nwg >> 3;                       // nwg % 8 == 0
  const int bid = blockIdx.x;
  const int swz = (bid & 7) * cpx + (bid >> 3);   // bijective XCD chunking
  const int bx  = swz % nbx;
  const int by  = swz / nbx;

  const int tid  = threadIdx.x;
  const int wave = tid >> 6;
  const int lane = tid & 63;
  const int rowBase = by * 256;
  const int colBase = bx * 256;
  const int wr = wave >> 2;          // 0..1  (row block of 128)
  const int wc = wave & 3;           // 0..3  (col block of 64)
  const int fr  = lane & 15;
  const int fob = (lane >> 4) * 16;  // byte offset within 64B row
  const int b   = rowBase >> 10;     // batch (256-row tile inside one batch)
  const int nn0 = rowBase & (N_ - 1);

  // staging source pointers: thread covers row (tid>>2), chunk (tid&3)
  const int srow = tid >> 2;         // 0..127
  const int scol = (tid & 3) * 8;    // element offset in K-tile row
  const bf16_t *Ap0, *Ap1, *Bp0, *Bp1;
  if (MODE == 3) {
    Ap0 = A + (size_t)b * (H_*N_*D_) + (size_t)(nn0 + srow) * D_ + scol;
    Ap1 = Ap0 + (size_t)128 * D_;
    const size_t bts = (size_t)b * C_ * C_;
    Bp0 = BT + bts + (size_t)(colBase + srow) * 768 + scol;
    Bp1 = Bp0 + (size_t)128 * 768;
  } else {
    Ap0 = A + (size_t)(rowBase + srow) * 768 + scol;
    Ap1 = Ap0 + (size_t)128 * 768;
    Bp0 = BT + (size_t)(colBase + srow) * 768 + scol;
    Bp1 = Bp0 + (size_t)128 * 768;
  }

  // fragment read byte offsets (within a buffer)
  const int aoff = (wr*128 + fr)*64 + fob;           // + m*1024
  const int boff = 16384 + (wc*64 + fr)*64 + fob;    // + n*1024

#define RDA(BI,MM) (*(const bf16x8*)(smem + (BI)*32768 + aoff + (MM)*1024))
#define RDB(BI,NN) (*(const bf16x8*)(smem + (BI)*32768 + boff + (NN)*1024))

#define A_OFF(K0) ((MODE == 3) ? ((size_t)((K0) >> 6) << 16) + ((K0) & 32) : (size_t)(K0))

#define STAGE_A(BI, T) do {                                                   \
    const int k0_ = (T) * 32;                                                 \
    const size_t ao_ = A_OFF(k0_);                                            \
    lds_load16(Ap0 + ao_, smem + (BI)*32768 + tid*16);                        \
    lds_load16(Ap1 + ao_, smem + (BI)*32768 + 8192 + tid*16);                 \
  } while (0)

#define STAGE_B(BI, T) do {                                                   \
    const int k0_ = (T) * 32;                                                 \
    lds_load16(Bp0 + k0_, smem + (BI)*32768 + 16384 + tid*16);                \
    lds_load16(Bp1 + k0_, smem + (BI)*32768 + 24576 + tid*16);                \
  } while (0)

  f32x4 acc[8][4];
  #pragma unroll
  for (int m = 0; m < 8; ++m)
    #pragma unroll
    for (int n = 0; n < 4; ++n) acc[m][n] = f32x4{0.f,0.f,0.f,0.f};

#define TILE(BI, T, DOST, VM) do {                                            \
    asm volatile("s_waitcnt vmcnt(" #VM ")" ::: "memory");                    \
    __builtin_amdgcn_sched_barrier(0);                                        \
    __builtin_amdgcn_s_barrier();                                             \
    __builtin_amdgcn_sched_barrier(0);                                        \
    if (DOST) STAGE_A(((BI)+3)&3, (T)+3);                                     \
    bf16x8 b0_=RDB(BI,0), b1_=RDB(BI,1), b2_=RDB(BI,2), b3_=RDB(BI,3);        \
    bf16x8 a0_=RDA(BI,0), a1_=RDA(BI,1), a2_=RDA(BI,2), a3_=RDA(BI,3);        \
    __builtin_amdgcn_s_setprio(1);                                            \
    acc[0][0]=MFMA16(a0_,b0_,acc[0][0]); acc[0][1]=MFMA16(a0_,b1_,acc[0][1]); \
    acc[0][2]=MFMA16(a0_,b2_,acc[0][2]); acc[0][3]=MFMA16(a0_,b3_,acc[0][3]); \
    acc[1][0]=MFMA16(a1_,b0_,acc[1][0]); acc[1][1]=MFMA16(a1_,b1_,acc[1][1]); \
    acc[1][2]=MFMA16(a1_,b2_,acc[1][2]); acc[1][3]=MFMA16(a1_,b3_,acc[1][3]); \
    acc[2][0]=MFMA16(a2_,b0_,acc[2][0]); acc[2][1]=MFMA16(a2_,b1_,acc[2][1]); \
    acc[2][2]=MFMA16(a2_,b2_,acc[2][2]); acc[2][3]=MFMA16(a2_,b3_,acc[2][3]); \
    acc[3][0]=MFMA16(a3_,b0_,acc[3][0]); acc[3][1]=MFMA16(a3_,b1_,acc[3][1]); \
    acc[3][2]=MFMA16(a3_,b2_,acc[3][2]); acc[3][3]=MFMA16(a3_,b3_,acc[3][3]); \
    __builtin_amdgcn_s_setprio(0);                                            \
    if (DOST) STAGE_B(((BI)+3)&3, (T)+3);                                     \
    a0_=RDA(BI,4); a1_=RDA(BI,5); a2_=RDA(BI,6); a3_=RDA(BI,7);               \
    __builtin_amdgcn_s_setprio(1);                                            \
    acc[4][0]=MFMA16(a0_,b0_,acc[4][0]); acc[4][1]=MFMA16(a0_,b1_,acc[4][1]); \
    acc[4][2]=MFMA16(a0_,b2_,acc[4][2]); acc[4][3]=MFMA16(a0_,b3_,acc[4][3]); \
    acc[5][0]=MFMA16(a1_,b0_,acc[5][0]); acc[5][1]=MFMA16(a1_,b1_,acc[5][1]); \
    acc[5][2]=MFMA16(a1_,b2_,acc[5][2]); acc[5][3]=MFMA16(a1_,b3_,acc[5][3]); \
    acc[6][0]=MFMA16(a2_,b0_,acc[6][0]); acc[6][1]=MFMA16(a2_,b1_,acc[6][1]); \
    acc[6][2]=MFMA16(a2_,b2_,acc[6][2]); acc[6][3]=MFMA16(a2_,b3_,acc[6][3]); \
    acc[7][0]=MFMA16(a3_,b0_,acc[7][0]); acc[7][1]=MFMA16(a3_,b1_,acc[7][1]); \
    acc[7][2]=MFMA16(a3_,b2_,acc[7][2]); acc[7][3]=MFMA16(a3_,b3_,acc[7][3]); \
    __builtin_amdgcn_s_setprio(0);                                            \
    asm volatile("s_waitcnt lgkmcnt(0)" ::: "memory");                        \
    __builtin_amdgcn_sched_barrier(0);                                        \
  } while (0)

  // prologue: stage tiles 0,1,2 into buffers 0,1,2 (12 loads in flight)
  STAGE_A(0,0); STAGE_B(0,0);
  STAGE_A(1,1); STAGE_B(1,1);
  STAGE_A(2,2); STAGE_B(2,2);

  #pragma unroll 1
  for (int t = 0; t < 20; t += 4) {
    TILE(0, t,   1, 8);
    TILE(1, t+1, 1, 8);
    TILE(2, t+2, 1, 8);
    TILE(3, t+3, 1, 8);
  }
  TILE(0, 20, 1, 8);   // stages tile 23
  TILE(1, 21, 0, 8);
  TILE(2, 22, 0, 4);
  TILE(3, 23, 0, 0);

#undef TILE
#undef STAGE_A
#undef STAGE_B
#undef A_OFF
#undef RDA
#undef RDB

  // ---------------------------------------------------------------- epilogue
  // C/D frag layout: row = wr*128 + m*16 + (lane>>4)*4 + j, col = wc*64 + n*16 + fr
  if (MODE == 3) {
    #pragma unroll
    for (int n = 0; n < 4; ++n) {
      const int gc = colBase + wc*64 + n*16 + fr;
      const float bb = bias[gc];
      #pragma unroll
      for (int m = 0; m < 8; ++m) {
        const int gr = rowBase + wr*128 + m*16 + ((lane >> 4) << 2);
        #pragma unroll
        for (int j = 0; j < 4; ++j)
          Cout[(size_t)(gr + j)*C_ + gc] = acc[m][n][j] + bb;
      }
    }
  } else {
    __syncthreads();   // main-loop LDS dead; reuse as transpose tile
    bf16_t* tile = (bf16_t*)smem;          // [128 cols][pitch 260 rows]
    const int s = colBase / C_;            // 0=q 1=k 2=v (256 | 768 -> uniform)
    #pragma unroll
    for (int ch = 0; ch < 2; ++ch) {       // column half of the 256-wide block
      if (ch) __syncthreads();
      if ((wc >> 1) == ch) {
        #pragma unroll
        for (int n = 0; n < 4; ++n) {
          const int cl = (wc & 1)*64 + n*16 + fr;          // 0..127
          const float bb = bias[colBase + ch*128 + cl];
          #pragma unroll
          for (int m = 0; m < 8; ++m) {
            const int r0 = wr*128 + m*16 + ((lane >> 4) << 2);
            bf16x4 hv;
            hv[0]=(bf16_t)(acc[m][n][0]+bb); hv[1]=(bf16_t)(acc[m][n][1]+bb);
            hv[2]=(bf16_t)(acc[m][n][2]+bb); hv[3]=(bf16_t)(acc[m][n][3]+bb);
            *(bf16x4*)&tile[cl*260 + r0] = hv;
          }
        }
      }
      __syncthreads();
      if (s == 0) {
        // q: row-major (b,h,n,d). thread: row r=tid>>1 (0..255), head-half hh=tid&1
        const int r = tid >> 1, hh = tid & 1;
        const int h = (colBase >> 6) + ch*2 + hh;
        bf16_t* dst = qh + (((size_t)b*H_ + h)*N_ + nn0 + r)*D_;
        #pragma unroll
        for (int i0 = 0; i0 < 64; i0 += 8) {
          bf16x8 vv;
          #pragma unroll
          for (int i = 0; i < 8; ++i) vv[i] = tile[(hh*64 + i0 + i)*260 + r];
          *(bf16x8*)&dst[i0] = vv;
        }
      } else {
        // k/v: (b,h,d,n). thread: col c=tid>>2 (0..127), row-quarter rq=tid&3
        const int c = tid >> 2, rq = tid & 3;
        const int rem = colBase + ch*128 + c - s*C_;
        const int h = rem >> 6, d = rem & 63;
        bf16_t* dst = (s == 1 ? kthi : vthi)
                      + (((size_t)b*H_ + h)*D_ + d)*N_ + nn0 + rq*64;
        #pragma unroll
        for (int i0 = 0; i0 < 64; i0 += 8)
          *(bf16x8*)&dst[i0] = *(const bf16x8*)&tile[c*260 + rq*64 + i0];
      }
    }
  }
}

// ---------------------------------------------------------------- stage 2: logits + softmax
// attnT[bh][e][d] = P[d][e], P = softmax_e( sum_n kt[d][n]*vt[e][n] / 8 )
__global__ __launch_bounds__(256, 2)
void attn_softmax_k(const bf16_t* __restrict__ kthi, const bf16_t* __restrict__ vthi,
                    bf16_t* __restrict__ attnT)
{
  __shared__ float tile[64][65];
  __shared__ float invs[64];
  const int bh = blockIdx.x;
  const int tid = threadIdx.x, wave = tid >> 6, lane = tid & 63;
  const int fr = lane & 15, fo = (lane >> 4) * 8;
  const size_t base = (size_t)bh * D_ * N_;
  f32x4 acc[4][4] = {{0.f,0.f,0.f,0.f}};
  const int k0lo = wave * 256;   // split-K across 4 waves
  #pragma unroll 1
  for (int k0 = k0lo; k0 < k0lo + 256; k0 += 32) {
    bf16x8 ah[4], bhv[4];
    #pragma unroll
    for (int m = 0; m < 4; ++m)
      ah[m] = *(const bf16x8*)&kthi[base + (size_t)(m*16 + fr)*N_ + k0 + fo];
    #pragma unroll
    for (int n = 0; n < 4; ++n)
      bhv[n] = *(const bf16x8*)&vthi[base + (size_t)(n*16 + fr)*N_ + k0 + fo];
    #pragma unroll
    for (int m = 0; m < 4; ++m)
      #pragma unroll
      for (int n = 0; n < 4; ++n)
        acc[m][n] = MFMA16(ah[m], bhv[n], acc[m][n]);
  }
  // cross-wave reduce into LDS
  for (int w = 0; w < 4; ++w) {
    if (wave == w) {
      #pragma unroll
      for (int m = 0; m < 4; ++m)
        #pragma unroll
        for (int n = 0; n < 4; ++n) {
          const int row = m*16 + ((lane >> 4) << 2);
          const int col = n*16 + fr;
          #pragma unroll
          for (int j = 0; j < 4; ++j) {
            if (w == 0) tile[row+j][col]  = acc[m][n][j];
            else        tile[row+j][col] += acc[m][n][j];
          }
        }
    }
    __syncthreads();
  }
  // row softmax (scale 1/8), one thread per row d
  if (tid < 64) {
    float mx = -3.0e38f;
    #pragma unroll
    for (int c = 0; c < 64; ++c) mx = fmaxf(mx, tile[tid][c]);
    mx *= 0.125f;
    float ssum = 0.f;
    #pragma unroll
    for (int c = 0; c < 64; ++c) {
      const float ev = __expf(tile[tid][c]*0.125f - mx);
      tile[tid][c] = ev;
      ssum += ev;
    }
    invs[tid] = 1.0f / ssum;
  }
  __syncthreads();
  // transposed write: thread e writes attnT[e][0..63] contiguous
  if (tid < 64) {
    bf16_t* ao = attnT + (size_t)bh * D_ * D_ + tid * D_;
    #pragma unroll
    for (int d0 = 0; d0 < 64; d0 += 8) {
      bf16x8 vv;
      #pragma unroll
      for (int i = 0; i < 8; ++i) vv[i] = (bf16_t)(tile[d0+i][tid] * invs[d0+i]);
      *(bf16x8*)&ao[d0] = vv;
    }
  }
}

// ---------------------------------------------------------------- stage 3: W' compose
// w2t[b][j][h*64+e] = sum_d woutT[j][h*64+d] * attnT[bh][e][d]
// grid (6, B*H), 256 threads (4 waves x 32 j-rows each)
__global__ __launch_bounds__(256, 2)
void compose_w2(const bf16_t* __restrict__ woutT, const bf16_t* __restrict__ attnT,
                bf16_t* __restrict__ w2t)
{
  const int jb = blockIdx.x;
  const int bh = blockIdx.y;
  const int b = bh / H_, h = bh - b*H_;
  const int tid = threadIdx.x, wave = tid >> 6, lane = tid & 63;
  const int fr = lane & 15, fo = (lane >> 4) * 8;
  const bf16_t* at = attnT + (size_t)bh * D_ * D_;
  f32x4 acc[2][4] = {{0.f,0.f,0.f,0.f}};
  #pragma unroll
  for (int kk = 0; kk < 2; ++kk) {
    bf16x8 af[2], bfv[4];
    #pragma unroll
    for (int m = 0; m < 2; ++m)
      af[m] = *(const bf16x8*)&woutT[(size_t)(jb*128 + wave*32 + m*16 + fr)*C_ + h*64 + kk*32 + fo];
    #pragma unroll
    for (int n = 0; n < 4; ++n)
      bfv[n] = *(const bf16x8*)&at[(n*16 + fr)*64 + kk*32 + fo];
    #pragma unroll
    for (int m = 0; m < 2; ++m)
      #pragma unroll
      for (int n = 0; n < 4; ++n)
        acc[m][n] = MFMA16(af[m], bfv[n], acc[m][n]);
  }
  bf16_t* wb = w2t + (size_t)b * C_ * C_;
  #pragma unroll
  for (int m = 0; m < 2; ++m) {
    const int j = jb*128 + wave*32 + m*16 + ((lane >> 4) << 2);
    #pragma unroll
    for (int n = 0; n < 4; ++n) {
      const int e = n*16 + fr;
      #pragma unroll
      for (int jj = 0; jj < 4; ++jj)
        wb[(size_t)(j + jj)*C_ + h*64 + e] = (bf16_t)acc[m][n][jj];
    }
  }
}

// ---------------------------------------------------------------- launcher
extern "C" void kernel_launch(void* const* d_in, const int* in_sizes, int n_in,
                              void* d_out, int out_size, void* d_ws, size_t ws_size,
                              hipStream_t stream)
{
  (void)in_sizes; (void)n_in; (void)out_size;
  const float* x     = (const float*)d_in[0];
  const float* w_qkv = (const float*)d_in[1];
  const float* b_qkv = (const float*)d_in[2];
  const float* w_out = (const float*)d_in[3];
  const float* b_out = (const float*)d_in[4];
  float* out = (float*)d_out;

  const size_t sz_xb   = (size_t)M_*C_*2;        // 50.3 MB
  const size_t sz_wq   = (size_t)TC_*C_*2;       //  3.5 MB
  const size_t sz_wo   = (size_t)C_*C_*2;        //  1.2 MB
  const size_t sz_qh   = (size_t)B_*H_*N_*D_*2;  // 50.3 MB
  const size_t sz_kv   = (size_t)B_*H_*D_*N_*2;  // 50.3 MB each
  const size_t sz_attn = (size_t)B_*H_*D_*D_*2;  //  3.1 MB

  char* p = (char*)d_ws;
  bf16_t* xb    = (bf16_t*)p; p += sz_xb;
  bf16_t* wqkvT = (bf16_t*)p; p += sz_wq;
  bf16_t* woutT = (bf16_t*)p; p += sz_wo;
  bf16_t* qh    = (bf16_t*)p; p += sz_qh;
  bf16_t* kthi  = (bf16_t*)p; p += sz_kv;
  bf16_t* vthi  = (bf16_t*)p; p += sz_kv;
  bf16_t* attnT = (bf16_t*)p; p += sz_attn;
  const size_t base_need = (size_t)(p - (char*)d_ws);
  // W' (32 x 768 x 768 bf16 = 37.7 MB) aliases xb (50.3 MB), dead after GEMM1
  bf16_t* w2t = xb;

  if (ws_size < base_need) return;   // leaves poison -> distinctive failure

  cvt_bf16<<<dim3((M_*C_)/2048), 256, 0, stream>>>(x, xb, M_*C_);
  transpose_cvt<<<dim3(TC_/32, C_/32), 256, 0, stream>>>(w_qkv, wqkvT, C_, TC_);
  transpose_cvt<<<dim3(C_/32,  C_/32), 256, 0, stream>>>(w_out, woutT, C_, C_);

  // GEMM1: qkv projection with scatter epilogue. grid = 9 x 128 = 1152 (8 | 1152)
  gemm_bt<1><<<dim3((TC_/256)*(M_/256)), 512, 0, stream>>>(
      xb, wqkvT, b_qkv, nullptr, qh, kthi, vthi, TC_/256);

  attn_softmax_k<<<dim3(B_*H_), 256, 0, stream>>>(kthi, vthi, attnT);

  compose_w2<<<dim3(C_/128, B_*H_), 256, 0, stream>>>(woutT, attnT, w2t);

  // GEMM2: out = qh(gathered) @ W'_b + b_out. grid = 3 x 128 = 384 (8 | 384)
  gemm_bt<3><<<dim3((C_/256)*(M_/256)), 512, 0, stream>>>(
      qh, w2t, b_out, out, nullptr, nullptr, nullptr, C_/256);
}